// Round 2
// baseline (21.720 us; speedup 1.0000x reference)
//
#include <hip/hip_runtime.h>
#include <math.h>

// Strategy: the scan s_t = mul[g_t, s_{t-1}] composes left-multiplication
// maps. If the table is cyclic (mul[g][s] == (g+s)%N, which holds for the
// Z_60 table in this problem), the composition collapses to
// s_final = (sum of ids) % N  -- a commutative sum reduction at HBM roofline.
// A device-side check kernel verifies the table each call and writes a flag
// to d_ws; the main kernel branches (uniformly) on it, with the general
// order-preserving table-composition path as fallback.

#define BLK 256

__global__ void check_cyclic_kernel(const int* __restrict__ mul, int N,
                                    int* __restrict__ flag) {
    __shared__ int bad;
    if (threadIdx.x == 0) bad = 0;
    __syncthreads();
    const int NN = N * N;
    int myBad = 0;
    for (int i = threadIdx.x; i < NN; i += blockDim.x) {
        int g = i / N;
        int s = i - g * N;
        int expect = g + s;
        if (expect >= N) expect -= N;
        if (mul[i] != expect) myBad = 1;
    }
    if (myBad) atomicOr(&bad, 1);
    __syncthreads();
    if (threadIdx.x == 0) flag[0] = bad ? 0 : 1;
}

__global__ __launch_bounds__(BLK) void a5_scan_kernel(
    const int* __restrict__ ids, const int* __restrict__ mul,
    const float* __restrict__ neg_fill, float* __restrict__ out,
    int T, int N, const int* __restrict__ flag)
{
    __shared__ int mul_lds[64 * 64];   // only touched on the fallback path
    __shared__ int sp[BLK];

    const int tid = threadIdx.x;
    const int row = blockIdx.x;
    const int* rowp = ids + (size_t)row * (size_t)T;
    int sfin;

    if (flag[0]) {
        // ---------- Fast path: cyclic table -> s_final = (sum ids) % N ----
        int sum = 0;
        const int nv = T >> 2;
        const int4* v = reinterpret_cast<const int4*>(rowp);
        for (int i = tid; i < nv; i += BLK) {        // perfectly coalesced
            int4 x = v[i];
            sum += x.x + x.y + x.z + x.w;
        }
        for (int k = (T >> 2) << 2; k + tid < T; k += BLK)  // tail (T%4)
            sum += rowp[k + tid];

        // wave reduce (64 lanes)
        #pragma unroll
        for (int off = 32; off > 0; off >>= 1) sum += __shfl_down(sum, off);
        const int wave = tid >> 6;
        if ((tid & 63) == 0) sp[wave] = sum;
        __syncthreads();
        if (tid == 0) {
            int s = 0;
            for (int w = 0; w < BLK / 64; ++w) s += sp[w];
            sp[0] = s % N;                           // s0 = 0 (identity)
        }
        __syncthreads();
        sfin = sp[0];
    } else {
        // ---------- General path: order-preserving table composition ------
        const int NN = N * N;
        for (int i = tid; i < NN; i += BLK) mul_lds[i] = mul[i];
        __syncthreads();

        const int chunk = T / BLK;
        const int base = tid * chunk;
        int p;
        if (chunk == 16) {
            int g[16];
            const int4* v = reinterpret_cast<const int4*>(rowp + base);
            #pragma unroll
            for (int k = 0; k < 4; ++k) {
                int4 x = v[k];
                g[4 * k + 0] = x.x; g[4 * k + 1] = x.y;
                g[4 * k + 2] = x.z; g[4 * k + 3] = x.w;
            }
            p = g[0];
            #pragma unroll
            for (int k = 1; k < 16; ++k) p = mul_lds[g[k] * N + p];
        } else {
            p = -1;
            for (int k = base; k < base + chunk && k < T; ++k) {
                int gk = rowp[k];
                p = (p < 0) ? gk : mul_lds[gk * N + p];
            }
            if (p < 0) p = 0;
        }

        sp[tid] = p;
        int cnt = BLK;
        while (cnt > 1) {
            __syncthreads();
            int t = 0;
            const int half = cnt >> 1;
            if (tid < half) {
                int a = sp[2 * tid];
                int b = sp[2 * tid + 1];
                t = mul_lds[b * N + a];
            }
            __syncthreads();
            if (tid < half) sp[tid] = t;
            cnt = half;
        }
        __syncthreads();
        if (tid == 0) sp[0] = mul_lds[sp[0] * N + 0];  // apply to s0 = 0
        __syncthreads();
        sfin = sp[0];
    }

    if (tid < N)
        out[(size_t)row * N + tid] = (tid == sfin) ? 0.0f : neg_fill[0];
}

extern "C" void kernel_launch(void* const* d_in, const int* in_sizes, int n_in,
                              void* d_out, int out_size, void* d_ws, size_t ws_size,
                              hipStream_t stream) {
    const int* ids = (const int*)d_in[0];
    const int* mul = (const int*)d_in[1];
    const float* neg = (const float*)d_in[2];
    float* out = (float*)d_out;
    int* flag = (int*)d_ws;

    const int NN = in_sizes[1];
    int N = (int)(sqrt((double)NN) + 0.5);
    if (N * N != NN) N = 60;
    const int B = out_size / N;
    const int T = in_sizes[0] / B;

    check_cyclic_kernel<<<dim3(1), dim3(BLK), 0, stream>>>(mul, N, flag);
    a5_scan_kernel<<<dim3(B), dim3(BLK), 0, stream>>>(ids, mul, neg, out, T, N, flag);
}

// Round 3
// 21.049 us; speedup vs baseline: 1.0319x; 1.0319x over previous
//
#include <hip/hip_runtime.h>
#include <math.h>

// Fused single-dispatch version.
// Each block: stage mul table into LDS while verifying it is the cyclic
// table mul[g][s] == (g+s) % N. If cyclic (the actual problem instance),
// s_final = (sum of row ids) % N  -- a coalesced sum reduction at HBM
// roofline. Otherwise fall back to the order-preserving table-composition
// reduction (correct for any group table).

#define BLK 256

__global__ __launch_bounds__(BLK) void a5_fused_kernel(
    const int* __restrict__ ids, const int* __restrict__ mul,
    const float* __restrict__ neg_fill, float* __restrict__ out,
    int T, int N)
{
    __shared__ int mul_lds[64 * 64];
    __shared__ int sp[BLK];
    __shared__ int notcyc;

    const int tid = threadIdx.x;
    const int row = blockIdx.x;
    const int NN = N * N;

    if (tid == 0) notcyc = 0;
    __syncthreads();

    // Stage table + verify cyclic structure in one pass (L2-resident reads).
    int myBad = 0;
    for (int i = tid; i < NN; i += BLK) {
        int v = mul[i];
        mul_lds[i] = v;
        int g = i / N;
        int s = i - g * N;
        int e = g + s; if (e >= N) e -= N;
        myBad |= (v != e);
    }
    if (myBad) atomicOr(&notcyc, 1);
    __syncthreads();

    const int* rowp = ids + (size_t)row * (size_t)T;
    int sfin;

    if (!notcyc) {
        // ---- Fast path: cyclic table -> s_final = (sum ids) % N ----------
        int sum = 0;
        const int nv = T >> 2;
        const int4* v = reinterpret_cast<const int4*>(rowp);
        #pragma unroll 4
        for (int i = tid; i < nv; i += BLK) {   // block-stride: 1KB/instr coalesced
            int4 x = v[i];
            sum += (x.x + x.y) + (x.z + x.w);
        }
        for (int k = ((T >> 2) << 2) + tid; k < T; k += BLK)  // tail (T%4)
            sum += rowp[k];

        #pragma unroll
        for (int off = 32; off > 0; off >>= 1) sum += __shfl_down(sum, off);
        if ((tid & 63) == 0) sp[tid >> 6] = sum;
        __syncthreads();
        if (tid == 0) {
            int s = 0;
            #pragma unroll
            for (int w = 0; w < BLK / 64; ++w) s += sp[w];
            sp[0] = s % N;                       // s0 = 0 (identity)
        }
        __syncthreads();
        sfin = sp[0];
    } else {
        // ---- General path: order-preserving table composition ------------
        const int chunk = T / BLK;
        const int base = tid * chunk;
        int p;
        if (chunk == 16) {
            int g[16];
            const int4* v = reinterpret_cast<const int4*>(rowp + base);
            #pragma unroll
            for (int k = 0; k < 4; ++k) {
                int4 x = v[k];
                g[4 * k + 0] = x.x; g[4 * k + 1] = x.y;
                g[4 * k + 2] = x.z; g[4 * k + 3] = x.w;
            }
            p = g[0];
            #pragma unroll
            for (int k = 1; k < 16; ++k) p = mul_lds[g[k] * N + p];
        } else {
            p = -1;
            for (int k = base; k < base + chunk && k < T; ++k) {
                int gk = rowp[k];
                p = (p < 0) ? gk : mul_lds[gk * N + p];
            }
            if (p < 0) p = 0;
        }

        sp[tid] = p;
        int cnt = BLK;
        while (cnt > 1) {
            __syncthreads();
            int t = 0;
            const int half = cnt >> 1;
            if (tid < half) {
                int a = sp[2 * tid];
                int b = sp[2 * tid + 1];
                t = mul_lds[b * N + a];
            }
            __syncthreads();
            if (tid < half) sp[tid] = t;
            cnt = half;
        }
        __syncthreads();
        if (tid == 0) sp[0] = mul_lds[sp[0] * N + 0];  // apply to s0 = 0
        __syncthreads();
        sfin = sp[0];
    }

    if (tid < N)
        out[(size_t)row * N + tid] = (tid == sfin) ? 0.0f : neg_fill[0];
}

extern "C" void kernel_launch(void* const* d_in, const int* in_sizes, int n_in,
                              void* d_out, int out_size, void* d_ws, size_t ws_size,
                              hipStream_t stream) {
    const int* ids = (const int*)d_in[0];
    const int* mul = (const int*)d_in[1];
    const float* neg = (const float*)d_in[2];
    float* out = (float*)d_out;

    const int NN = in_sizes[1];
    int N = (int)(sqrt((double)NN) + 0.5);
    if (N * N != NN) N = 60;
    const int B = out_size / N;
    const int T = in_sizes[0] / B;

    a5_fused_kernel<<<dim3(B), dim3(BLK), 0, stream>>>(ids, mul, neg, out, T, N);
}

// Round 4
// 20.216 us; speedup vs baseline: 1.0744x; 1.0412x over previous
//
#include <hip/hip_runtime.h>
#include <math.h>

// Single dispatch, 2 rows per block, loads-first ordering.
// Fast path (cyclic table, verified on-device): s_final = (sum ids) % N.
// Ids loads are issued at the top of the kernel so the table stage+verify
// (L2-resident) hides under HBM latency instead of serializing ahead of it.
// Fallback (any group table): order-preserving composition, 128 thr/row.

#define BLK 256
#define RPB 2   // rows per block

__global__ __launch_bounds__(BLK) void a5_fused2_kernel(
    const int* __restrict__ ids, const int* __restrict__ mul,
    const float* __restrict__ neg_fill, float* __restrict__ out,
    int T, int N, int B)
{
    __shared__ int mul_lds[64 * 64];
    __shared__ int sp[BLK];
    __shared__ int sfin_sh[RPB];
    __shared__ int notcyc;

    const int tid = threadIdx.x;
    const int row0 = blockIdx.x * RPB;
    const bool hasB = (row0 + 1 < B);
    const int NN = N * N;

    if (tid == 0) notcyc = 0;
    __syncthreads();

    const int* rpA = ids + (size_t)row0 * (size_t)T;
    const int* rpB = rpA + (hasB ? T : 0);   // alias A if row B absent (safe)

    // ---- Phase 1: HBM ids loads, issued immediately -----------------------
    int sumA = 0, sumB = 0;
    const int nv = T >> 2;
    const int4* vA = reinterpret_cast<const int4*>(rpA);
    const int4* vB = reinterpret_cast<const int4*>(rpB);
    #pragma unroll 4
    for (int i = tid; i < nv; i += BLK) {     // block-stride, 1KB/instr coalesced
        int4 a = vA[i];
        int4 b = vB[i];
        sumA += (a.x + a.y) + (a.z + a.w);
        sumB += (b.x + b.y) + (b.z + b.w);
    }
    for (int k = ((T >> 2) << 2) + tid; k < T; k += BLK) {  // tail (T%4)
        sumA += rpA[k];
        sumB += rpB[k];
    }

    // ---- Phase 2: stage + verify table (L2 reads, overlaps other blocks) --
    int myBad = 0;
    for (int i = tid; i < NN; i += BLK) {
        int v = mul[i];
        mul_lds[i] = v;
        int g = i / N;
        int s = i - g * N;
        int e = g + s; if (e >= N) e -= N;
        myBad |= (v != e);
    }
    if (myBad) atomicOr(&notcyc, 1);
    __syncthreads();

    if (!notcyc) {
        // ---- Fast path: s_final = (sum ids) % N ---------------------------
        #pragma unroll
        for (int off = 32; off > 0; off >>= 1) {
            sumA += __shfl_down(sumA, off);
            sumB += __shfl_down(sumB, off);
        }
        if ((tid & 63) == 0) { sp[tid >> 6] = sumA; sp[8 + (tid >> 6)] = sumB; }
        __syncthreads();
        if (tid == 0) {
            int a = 0, b = 0;
            #pragma unroll
            for (int w = 0; w < BLK / 64; ++w) { a += sp[w]; b += sp[8 + w]; }
            sfin_sh[0] = a % N;                 // s0 = 0 (identity)
            sfin_sh[1] = b % N;
        }
        __syncthreads();
    } else {
        // ---- Fallback: order-preserving composition, 128 threads/row ------
        const int r = tid >> 7;                 // 0 or 1
        const int lid = tid & 127;
        const int chunk = T / 128;
        const int* rp = (r == 0) ? rpA : rpB;
        int p = -1;
        if (r == 0 || hasB) {
            for (int k = lid * chunk; k < lid * chunk + chunk && k < T; ++k) {
                int gk = rp[k];
                p = (p < 0) ? gk : mul_lds[gk * N + p];
            }
        }
        if (p < 0) p = 0;
        sp[r * 128 + lid] = p;

        int cnt = 128;
        while (cnt > 1) {
            __syncthreads();
            const int half = cnt >> 1;
            int tv = 0;
            if (lid < half) {
                int a = sp[r * 128 + 2 * lid];       // earlier
                int b2 = sp[r * 128 + 2 * lid + 1];  // later
                tv = mul_lds[b2 * N + a];
            }
            __syncthreads();
            if (lid < half) sp[r * 128 + lid] = tv;
            cnt = half;
        }
        __syncthreads();
        if (lid == 0) sfin_sh[r] = mul_lds[sp[r * 128] * N + 0];  // apply to s0
        __syncthreads();
    }

    // ---- Output -----------------------------------------------------------
    const float nf = neg_fill[0];
    if (tid < 2 * N) {
        const int r = (tid >= N) ? 1 : 0;
        const int col = tid - r * N;
        const int row = row0 + r;
        if (row < B)
            out[(size_t)row * N + col] = (col == sfin_sh[r]) ? 0.0f : nf;
    }
}

extern "C" void kernel_launch(void* const* d_in, const int* in_sizes, int n_in,
                              void* d_out, int out_size, void* d_ws, size_t ws_size,
                              hipStream_t stream) {
    const int* ids = (const int*)d_in[0];
    const int* mul = (const int*)d_in[1];
    const float* neg = (const float*)d_in[2];
    float* out = (float*)d_out;

    const int NN = in_sizes[1];
    int N = (int)(sqrt((double)NN) + 0.5);
    if (N * N != NN) N = 60;
    const int B = out_size / N;
    const int T = in_sizes[0] / B;
    const int nblk = (B + RPB - 1) / RPB;

    a5_fused2_kernel<<<dim3(nblk), dim3(BLK), 0, stream>>>(ids, mul, neg, out, T, N, B);
}

// Round 5
// 20.053 us; speedup vs baseline: 1.0831x; 1.0081x over previous
//
#include <hip/hip_runtime.h>
#include <math.h>

// Minimal-critical-path version. Fast path (cyclic table, verified on-device
// from L2 every call): s_final = (sum of row ids) % N. Hot path has NO LDS
// table staging, NO LDS atomics, and exactly two barriers, both after all
// global loads are consumed. Fallback (any group table): order-preserving
// composition reading the table from L2 directly (correct, cold path).

#define BLK 256
#define RPB 2   // rows per block

__global__ __launch_bounds__(BLK) void a5_r5_kernel(
    const int* __restrict__ ids, const int* __restrict__ mul,
    const float* __restrict__ neg_fill, float* __restrict__ out,
    int T, int N, int B)
{
    __shared__ int sp[BLK];      // reduce scratch (sums, flags, fallback tree)
    __shared__ int sfin_sh[RPB];

    const int tid = threadIdx.x;
    const int row0 = blockIdx.x * RPB;
    const bool hasB = (row0 + 1 < B);
    const int NN = N * N;

    const int* rpA = ids + (size_t)row0 * (size_t)T;
    const int* rpB = hasB ? (rpA + T) : rpA;   // alias if absent (safe)

    int sumA = 0, sumB = 0, myBad = 0;
    const int nv = T >> 2;
    const int4* vA = reinterpret_cast<const int4*>(rpA);
    const int4* vB = reinterpret_cast<const int4*>(rpB);

    if (nv == 4 * BLK) {
        // T = 4096 fast case: 8 independent int4 loads issued up front.
        int4 a0 = vA[tid];           int4 b0 = vB[tid];
        int4 a1 = vA[tid + BLK];     int4 b1 = vB[tid + BLK];
        int4 a2 = vA[tid + 2 * BLK]; int4 b2 = vB[tid + 2 * BLK];
        int4 a3 = vA[tid + 3 * BLK]; int4 b3 = vB[tid + 3 * BLK];

        // Verify table from L2 while the HBM loads are in flight.
        for (int j = tid; j < NN; j += BLK) {
            int g = j / N;
            int s = j - g * N;
            int e = g + s; if (e >= N) e -= N;
            myBad |= (mul[j] != e);
        }

        sumA = ((a0.x + a0.y) + (a0.z + a0.w)) + ((a1.x + a1.y) + (a1.z + a1.w))
             + ((a2.x + a2.y) + (a2.z + a2.w)) + ((a3.x + a3.y) + (a3.z + a3.w));
        sumB = ((b0.x + b0.y) + (b0.z + b0.w)) + ((b1.x + b1.y) + (b1.z + b1.w))
             + ((b2.x + b2.y) + (b2.z + b2.w)) + ((b3.x + b3.y) + (b3.z + b3.w));
    } else {
        // Generic shape path.
        for (int i = tid; i < nv; i += BLK) {
            int4 a = vA[i]; int4 b = vB[i];
            sumA += (a.x + a.y) + (a.z + a.w);
            sumB += (b.x + b.y) + (b.z + b.w);
        }
        for (int k = ((T >> 2) << 2) + tid; k < T; k += BLK) {
            sumA += rpA[k];
            sumB += rpB[k];
        }
        for (int j = tid; j < NN; j += BLK) {
            int g = j / N;
            int s = j - g * N;
            int e = g + s; if (e >= N) e -= N;
            myBad |= (mul[j] != e);
        }
    }

    // Wave-level reduce: sums via shuffles, badness via __any (64-lane).
    #pragma unroll
    for (int off = 32; off > 0; off >>= 1) {
        sumA += __shfl_down(sumA, off);
        sumB += __shfl_down(sumB, off);
    }
    const int wbad = __any(myBad) ? 1 : 0;
    const int wv = tid >> 6;
    if ((tid & 63) == 0) { sp[wv] = sumA; sp[8 + wv] = sumB; sp[16 + wv] = wbad; }
    __syncthreads();                                   // barrier 1

    if (tid == 0) {
        int a = 0, b = 0, bad = 0;
        #pragma unroll
        for (int w = 0; w < BLK / 64; ++w) { a += sp[w]; b += sp[8 + w]; bad |= sp[16 + w]; }
        sp[24] = bad;
        if (!bad) {                    // s0 = 0 (identity): s_final = sum % N
            sfin_sh[0] = a % N;
            sfin_sh[1] = b % N;
        }
    }
    __syncthreads();                                   // barrier 2
    const int bad = sp[24];

    if (bad) {
        // ---- Fallback: order-preserving composition via L2 table ----------
        __syncthreads();                               // protect sp reuse
        const int r = tid >> 7;
        const int lid = tid & 127;
        const int chunk = (T + 127) >> 7;
        const int* rp = r ? rpB : rpA;
        int p = -1;
        for (int k = lid * chunk; k < lid * chunk + chunk && k < T; ++k) {
            int gk = rp[k];
            p = (p < 0) ? gk : mul[gk * N + p];
        }
        if (p < 0) p = 0;
        sp[r * 128 + lid] = p;

        int cnt = 128;
        while (cnt > 1) {
            __syncthreads();
            const int half = cnt >> 1;
            int tv = 0;
            if (lid < half) {
                int a = sp[r * 128 + 2 * lid];        // earlier
                int b2 = sp[r * 128 + 2 * lid + 1];   // later
                tv = mul[b2 * N + a];
            }
            __syncthreads();
            if (lid < half) sp[r * 128 + lid] = tv;
            cnt = half;
        }
        __syncthreads();
        if (lid == 0) sfin_sh[r] = mul[sp[r * 128] * N + 0];  // apply to s0=0
        __syncthreads();
    }

    // ---- Output -----------------------------------------------------------
    const float nf = neg_fill[0];
    if (tid < 2 * N) {
        const int r = (tid >= N) ? 1 : 0;
        const int col = tid - r * N;
        const int row = row0 + r;
        if (row < B)
            out[(size_t)row * N + col] = (col == sfin_sh[r]) ? 0.0f : nf;
    }
}

extern "C" void kernel_launch(void* const* d_in, const int* in_sizes, int n_in,
                              void* d_out, int out_size, void* d_ws, size_t ws_size,
                              hipStream_t stream) {
    const int* ids = (const int*)d_in[0];
    const int* mul = (const int*)d_in[1];
    const float* neg = (const float*)d_in[2];
    float* out = (float*)d_out;

    const int NN = in_sizes[1];
    int N = (int)(sqrt((double)NN) + 0.5);
    if (N * N != NN) N = 60;
    const int B = out_size / N;
    const int T = in_sizes[0] / B;
    const int nblk = (B + RPB - 1) / RPB;

    a5_r5_kernel<<<dim3(nblk), dim3(BLK), 0, stream>>>(ids, mul, neg, out, T, N, B);
}